// Round 3
// baseline (576.479 us; speedup 1.0000x reference)
//
#include <hip/hip_runtime.h>
#include <hip/hip_bf16.h>

// KronLinear: out = x @ (sum_r kron(a_r, b_r)) + bias
// M=8192 tokens, K=4096=(i,k_b), N=4096=(j,l), RANK=64.
// R2->R3: gemm inner op 16x16x32 -> 32x32x16 (17% less MFMA-pipe time);
// build_w re-blocked for 4x less L2 traffic.

#define M_DIM 8192
#define N_DIM 4096
#define K_DIM 4096
#define KT_COUNT 128   // K_DIM / 32

typedef __attribute__((ext_vector_type(8))) short short8;
typedef __attribute__((ext_vector_type(4))) short short4v;
typedef __attribute__((ext_vector_type(4))) float floatx4;
typedef __attribute__((ext_vector_type(16))) float floatx16;

typedef __attribute__((address_space(1))) void gvoid_t;
typedef __attribute__((address_space(3))) void lvoid_t;

static __device__ __forceinline__ void gl_lds16(const void* g, const void* l) {
  __builtin_amdgcn_global_load_lds((gvoid_t*)(unsigned long long)g,
                                   (lvoid_t*)(unsigned int)(unsigned long long)l,
                                   16, 0, 0);
}

static __device__ __forceinline__ unsigned short f2bf(float f) {
  unsigned int u = __builtin_bit_cast(unsigned int, f);
  u = (u + 0x7fffu + ((u >> 16) & 1u)) >> 16;  // RNE
  return (unsigned short)u;
}

// ---------------------------------------------------------------------------
// Fused prep: blocks [0,1024) build W^T packed; blocks [1024,9216) pack x.
//
// Packed blob (T0, kt) = 128 rows x 32 k: chunk p = c*128 + mm holds
// row (T0*128+mm), k = kt*32 + c*8 .. +7, as 8 bf16 (16B). Identical layout
// for Xp (rows = tokens) and Wp (rows = n = j*64+l).
// ---------------------------------------------------------------------------
__global__ __launch_bounds__(256) void prep_kernel(
    const float* __restrict__ x, const float* __restrict__ a,
    const float* __restrict__ b, unsigned short* __restrict__ Xp,
    unsigned short* __restrict__ Wp) {
  __shared__ float lds[128 * 33];  // build_w uses first 4096 floats
  const int bid = blockIdx.x;
  const int t = threadIdx.x;

  if (bid < 1024) {
    // ---- build W^T: wT[n=(j*64+l)][i*64+k_b] = sum_r a[r,i,j]*b[r,k_b,l]
    // Block = (i, all 64 j, 4 k_b).  Thread: l = t&63, jset = t>>6 (16 j's).
    const int i = bid >> 4;
    const int k0 = (bid & 15) * 4;

    {  // stage a[r, i, 0..63] for all r: 4096 floats, [r][64 j]
#pragma unroll
      for (int q = 0; q < 4; ++q) {
        const int idx = q * 256 + t;
        const int r = idx >> 4, jq = idx & 15;
        float4 v = ((const float4*)(a + (size_t)r * 4096 + i * 64))[jq];
        ((float4*)lds)[r * 16 + jq] = v;
      }
    }
    __syncthreads();

    const int l = t & 63;
    const int jset = t >> 6;  // 0..3 -> j = jset*16 + jj
    float acc[16][4];
#pragma unroll
    for (int jj = 0; jj < 16; ++jj)
#pragma unroll
      for (int kb = 0; kb < 4; ++kb) acc[jj][kb] = 0.f;

    const float* bb = b + k0 * 64 + l;
#pragma unroll 2
    for (int r = 0; r < 64; ++r) {
      float bv[4];
#pragma unroll
      for (int kb = 0; kb < 4; ++kb) bv[kb] = bb[(size_t)r * 4096 + kb * 64];
      float av[16];
#pragma unroll
      for (int jq = 0; jq < 4; ++jq) {
        float4 aj = ((const float4*)lds)[r * 16 + jset * 4 + jq];  // broadcast
        av[jq * 4 + 0] = aj.x; av[jq * 4 + 1] = aj.y;
        av[jq * 4 + 2] = aj.z; av[jq * 4 + 3] = aj.w;
      }
#pragma unroll
      for (int jj = 0; jj < 16; ++jj)
#pragma unroll
        for (int kb = 0; kb < 4; ++kb)
          acc[jj][kb] = fmaf(av[jj], bv[kb], acc[jj][kb]);
    }

    // write: kk = i*64 + k0 + kb; 4 kb = half a 16B chunk -> 8B stores
    const int kt = (i * 64 + k0) >> 5;
    const int c = (k0 & 31) >> 3;
    const int half = (k0 >> 2) & 1;
#pragma unroll
    for (int jj = 0; jj < 16; ++jj) {
      const int j = jset * 16 + jj;
      const int n = j * 64 + l;
      const int blob = (n >> 7) * KT_COUNT + kt;
      const int pos = c * 128 + (n & 127);
      short4v o;
#pragma unroll
      for (int kb = 0; kb < 4; ++kb) o[kb] = (short)f2bf(acc[jj][kb]);
      *(short4v*)(Wp + (size_t)blob * 4096 + pos * 8 + half * 4) = o;
    }
  } else {
    // ---- pack x
    const int pid = bid - 1024;
    const int kt = pid & 127;
    const int M0 = pid >> 7;

    {  // load 128 rows x 32 floats, coalesced (2 threads/row, 64B each)
      const int row = t >> 1;
      const int half = t & 1;
      const float* src = x + (size_t)(M0 * 128 + row) * K_DIM + kt * 32 + half * 16;
      float v[16];
#pragma unroll
      for (int w = 0; w < 4; ++w) {
        float4 vv = ((const float4*)src)[w];
        v[w * 4 + 0] = vv.x; v[w * 4 + 1] = vv.y;
        v[w * 4 + 2] = vv.z; v[w * 4 + 3] = vv.w;
      }
#pragma unroll
      for (int e = 0; e < 16; ++e) lds[row * 33 + half * 16 + e] = v[e];
    }
    __syncthreads();

    unsigned short* dst = Xp + (size_t)(M0 * KT_COUNT + kt) * 4096;
#pragma unroll
    for (int q = 0; q < 2; ++q) {
      const int p = q * 256 + t;
      const int c = p >> 7, mm = p & 127;
      short8 o;
#pragma unroll
      for (int j = 0; j < 8; ++j) o[j] = (short)f2bf(lds[mm * 33 + c * 8 + j]);
      *(short8*)(dst + p * 8) = o;
    }
  }
}

// ---------------------------------------------------------------------------
// GEMM: C = Xp @ Wp^T + bias.  128x128 tile, BK=32, 4 waves (2x2),
// each wave 2x2 tiles of 32x32x16 bf16 MFMA (20% better FLOP/cyc than 16x16).
// XCD swizzle: bid%8 -> XCD owns N0 in [xcd*4, xcd*4+4) (4MB Wp slice),
// M-major within XCD so same-M0 blocks are concurrent.
// ---------------------------------------------------------------------------
__global__ __launch_bounds__(256) void gemm_kernel(
    const unsigned short* __restrict__ Xp, const unsigned short* __restrict__ Wp,
    const float* __restrict__ bias, float* __restrict__ out) {
  __shared__ short8 As[512];  // 8KB: chunk idx = c*128 + m
  __shared__ short8 Bs[512];  // 8KB: chunk idx = c*128 + n

  const int bid = blockIdx.x;
  const int xcd = bid & 7;
  const int pos = bid >> 3;            // 0..255
  const int N0 = xcd * 4 + (pos & 3);  // 0..31
  const int M0 = pos >> 2;             // 0..63

  const int t = threadIdx.x;
  const int wave = t >> 6, lane = t & 63;
  const int l32 = lane & 31, hl = lane >> 5;
  const int wm = wave & 1, wn = wave >> 1;

  floatx16 acc[2][2];
#pragma unroll
  for (int mt = 0; mt < 2; ++mt)
#pragma unroll
    for (int nt = 0; nt < 2; ++nt)
#pragma unroll
      for (int r = 0; r < 16; ++r) acc[mt][nt][r] = 0.f;

  const unsigned short* pa = Xp + (size_t)M0 * KT_COUNT * 4096 + (size_t)t * 8;
  const unsigned short* pb = Wp + (size_t)N0 * KT_COUNT * 4096 + (size_t)t * 8;
  const short8* lA0 = As + wave * 64;  // wave-uniform LDS bases
  const short8* lA1 = As + 256 + wave * 64;
  const short8* lB0 = Bs + wave * 64;
  const short8* lB1 = Bs + 256 + wave * 64;

  for (int kt = 0; kt < KT_COUNT; ++kt) {
    __syncthreads();
    gl_lds16(pa, lA0);
    gl_lds16(pa + 2048, lA1);
    gl_lds16(pb, lB0);
    gl_lds16(pb + 2048, lB1);
    pa += 4096;
    pb += 4096;
    __syncthreads();

#pragma unroll
    for (int ks = 0; ks < 2; ++ks) {
      const int c = ks * 2 + hl;  // k-octet for this lane-half
      short8 af[2], bf[2];
#pragma unroll
      for (int mt = 0; mt < 2; ++mt)
        af[mt] = As[c * 128 + wm * 64 + mt * 32 + l32];
#pragma unroll
      for (int nt = 0; nt < 2; ++nt)
        bf[nt] = Bs[c * 128 + wn * 64 + nt * 32 + l32];
#pragma unroll
      for (int mt = 0; mt < 2; ++mt)
#pragma unroll
        for (int nt = 0; nt < 2; ++nt)
          acc[mt][nt] = __builtin_amdgcn_mfma_f32_32x32x16_bf16(
              af[mt], bf[nt], acc[mt][nt], 0, 0, 0);
    }
  }

  // C/D layout (32x32): col = lane&31, row = (r&3) + 8*(r>>2) + 4*(lane>>5)
  const int col_base = N0 * 128 + wn * 64;
  const int row_base = M0 * 128 + wm * 64 + 4 * hl;
#pragma unroll
  for (int nt = 0; nt < 2; ++nt) {
    const int col = col_base + nt * 32 + l32;
    const float bv = bias[col];
#pragma unroll
    for (int mt = 0; mt < 2; ++mt) {
      floatx16 v = acc[mt][nt];
#pragma unroll
      for (int r = 0; r < 16; ++r) {
        const int row = row_base + mt * 32 + (r & 3) + 8 * (r >> 2);
        out[(size_t)row * N_DIM + col] = v[r] + bv;
      }
    }
  }
}

extern "C" void kernel_launch(void* const* d_in, const int* in_sizes, int n_in,
                              void* d_out, int out_size, void* d_ws, size_t ws_size,
                              hipStream_t stream) {
  const float* x = (const float*)d_in[0];     // 8192*4096
  const float* a = (const float*)d_in[1];     // 64*64*64 (r,i,j)
  const float* b = (const float*)d_in[2];     // 64*64*64 (r,k,l)
  const float* bias = (const float*)d_in[3];  // 4096
  float* out = (float*)d_out;

  unsigned short* Xp = (unsigned short*)d_ws;        // 67MB
  unsigned short* Wp = Xp + (size_t)M_DIM * K_DIM;   // 33.5MB

  prep_kernel<<<1024 + 8192, 256, 0, stream>>>(x, a, b, Xp, Wp);
  gemm_kernel<<<2048, 256, 0, stream>>>(Xp, Wp, bias, out);
}

// Round 4
// 531.736 us; speedup vs baseline: 1.0841x; 1.0841x over previous
//
#include <hip/hip_runtime.h>
#include <hip/hip_bf16.h>

// KronLinear: out = x @ (sum_r kron(a_r, b_r)) + bias
// M=8192 tokens, K=4096=(i,k_b), N=4096=(j,l), RANK=64.
// R3->R4: revert gemm to 16x16x32 (R3's 32x32 lost MFMA ILP: 4 dependent
// chains vs 16 independent); BK 32->64 to halve barrier-drain exposures.

#define M_DIM 8192
#define N_DIM 4096
#define K_DIM 4096
#define KT_COUNT 128   // K_DIM / 32

typedef __attribute__((ext_vector_type(8))) short short8;
typedef __attribute__((ext_vector_type(4))) short short4v;
typedef __attribute__((ext_vector_type(4))) float floatx4;

typedef __attribute__((address_space(1))) void gvoid_t;
typedef __attribute__((address_space(3))) void lvoid_t;

static __device__ __forceinline__ void gl_lds16(const void* g, const void* l) {
  __builtin_amdgcn_global_load_lds((gvoid_t*)(unsigned long long)g,
                                   (lvoid_t*)(unsigned int)(unsigned long long)l,
                                   16, 0, 0);
}

static __device__ __forceinline__ unsigned short f2bf(float f) {
  unsigned int u = __builtin_bit_cast(unsigned int, f);
  u = (u + 0x7fffu + ((u >> 16) & 1u)) >> 16;  // RNE
  return (unsigned short)u;
}

// ---------------------------------------------------------------------------
// Fused prep: blocks [0,1024) build W^T packed; blocks [1024,9216) pack x.
// Packed blob (T0, kt) = 128 rows x 32 k: chunk p = c*128 + mm holds
// row (T0*128+mm), k = kt*32 + c*8 .. +7, as 8 bf16 (16B).
// ---------------------------------------------------------------------------
__global__ __launch_bounds__(256) void prep_kernel(
    const float* __restrict__ x, const float* __restrict__ a,
    const float* __restrict__ b, unsigned short* __restrict__ Xp,
    unsigned short* __restrict__ Wp) {
  __shared__ float lds[128 * 33];
  const int bid = blockIdx.x;
  const int t = threadIdx.x;

  if (bid < 1024) {
    // ---- build W^T: wT[n=(j*64+l)][i*64+k_b] = sum_r a[r,i,j]*b[r,k_b,l]
    const int i = bid >> 4;
    const int k0 = (bid & 15) * 4;

    {  // stage a[r, i, 0..63] for all r: 4096 floats, [r][64 j]
#pragma unroll
      for (int q = 0; q < 4; ++q) {
        const int idx = q * 256 + t;
        const int r = idx >> 4, jq = idx & 15;
        float4 v = ((const float4*)(a + (size_t)r * 4096 + i * 64))[jq];
        ((float4*)lds)[r * 16 + jq] = v;
      }
    }
    __syncthreads();

    const int l = t & 63;
    const int jset = t >> 6;
    float acc[16][4];
#pragma unroll
    for (int jj = 0; jj < 16; ++jj)
#pragma unroll
      for (int kb = 0; kb < 4; ++kb) acc[jj][kb] = 0.f;

    const float* bb = b + k0 * 64 + l;
#pragma unroll 2
    for (int r = 0; r < 64; ++r) {
      float bv[4];
#pragma unroll
      for (int kb = 0; kb < 4; ++kb) bv[kb] = bb[(size_t)r * 4096 + kb * 64];
      float av[16];
#pragma unroll
      for (int jq = 0; jq < 4; ++jq) {
        float4 aj = ((const float4*)lds)[r * 16 + jset * 4 + jq];
        av[jq * 4 + 0] = aj.x; av[jq * 4 + 1] = aj.y;
        av[jq * 4 + 2] = aj.z; av[jq * 4 + 3] = aj.w;
      }
#pragma unroll
      for (int jj = 0; jj < 16; ++jj)
#pragma unroll
        for (int kb = 0; kb < 4; ++kb)
          acc[jj][kb] = fmaf(av[jj], bv[kb], acc[jj][kb]);
    }

    const int kt = (i * 64 + k0) >> 5;
    const int c = (k0 & 31) >> 3;
    const int half = (k0 >> 2) & 1;
#pragma unroll
    for (int jj = 0; jj < 16; ++jj) {
      const int j = jset * 16 + jj;
      const int n = j * 64 + l;
      const int blob = (n >> 7) * KT_COUNT + kt;
      const int pos = c * 128 + (n & 127);
      short4v o;
#pragma unroll
      for (int kb = 0; kb < 4; ++kb) o[kb] = (short)f2bf(acc[jj][kb]);
      *(short4v*)(Wp + (size_t)blob * 4096 + pos * 8 + half * 4) = o;
    }
  } else {
    // ---- pack x
    const int pid = bid - 1024;
    const int kt = pid & 127;
    const int M0 = pid >> 7;

    {
      const int row = t >> 1;
      const int half = t & 1;
      const float* src = x + (size_t)(M0 * 128 + row) * K_DIM + kt * 32 + half * 16;
      float v[16];
#pragma unroll
      for (int w = 0; w < 4; ++w) {
        float4 vv = ((const float4*)src)[w];
        v[w * 4 + 0] = vv.x; v[w * 4 + 1] = vv.y;
        v[w * 4 + 2] = vv.z; v[w * 4 + 3] = vv.w;
      }
#pragma unroll
      for (int e = 0; e < 16; ++e) lds[row * 33 + half * 16 + e] = v[e];
    }
    __syncthreads();

    unsigned short* dst = Xp + (size_t)(M0 * KT_COUNT + kt) * 4096;
#pragma unroll
    for (int q = 0; q < 2; ++q) {
      const int p = q * 256 + t;
      const int c = p >> 7, mm = p & 127;
      short8 o;
#pragma unroll
      for (int j = 0; j < 8; ++j) o[j] = (short)f2bf(lds[mm * 33 + c * 8 + j]);
      *(short8*)(dst + p * 8) = o;
    }
  }
}

// ---------------------------------------------------------------------------
// GEMM: C = Xp @ Wp^T + bias.  128x128 tile, BK=64 (2 blobs/iter, 32KB LDS),
// 4 waves (2x2), each wave 4x4 tiles of 16x16x32 bf16 MFMA, 2 k-substeps.
// XCD swizzle: bid%8 -> XCD owns N0 in [xcd*4, xcd*4+4) (4MB Wp slice).
// ---------------------------------------------------------------------------
__global__ __launch_bounds__(256) void gemm_kernel(
    const unsigned short* __restrict__ Xp, const unsigned short* __restrict__ Wp,
    const float* __restrict__ bias, float* __restrict__ out) {
  __shared__ short8 As[1024];  // 16KB: blob ks at ks*512; chunk = c*128 + m
  __shared__ short8 Bs[1024];  // 16KB

  const int bid = blockIdx.x;
  const int xcd = bid & 7;
  const int pos = bid >> 3;            // 0..255
  const int N0 = xcd * 4 + (pos & 3);  // 0..31
  const int M0 = pos >> 2;             // 0..63

  const int t = threadIdx.x;
  const int wave = t >> 6, lane = t & 63;
  const int l16 = lane & 15, quad = lane >> 4;
  const int wm = wave & 1, wn = wave >> 1;

  floatx4 acc[4][4];
#pragma unroll
  for (int mt = 0; mt < 4; ++mt)
#pragma unroll
    for (int nt = 0; nt < 4; ++nt) acc[mt][nt] = (floatx4){0.f, 0.f, 0.f, 0.f};

  const unsigned short* pa = Xp + (size_t)M0 * KT_COUNT * 4096 + (size_t)t * 8;
  const unsigned short* pb = Wp + (size_t)N0 * KT_COUNT * 4096 + (size_t)t * 8;

  for (int kt = 0; kt < KT_COUNT / 2; ++kt) {
    __syncthreads();
#pragma unroll
    for (int q = 0; q < 4; ++q) {
      gl_lds16(pa + q * 2048, As + wave * 64 + q * 256);
      gl_lds16(pb + q * 2048, Bs + wave * 64 + q * 256);
    }
    pa += 8192;
    pb += 8192;
    __syncthreads();

#pragma unroll
    for (int ks = 0; ks < 2; ++ks) {
      short8 af[4], bf[4];
#pragma unroll
      for (int mt = 0; mt < 4; ++mt)
        af[mt] = As[ks * 512 + quad * 128 + wm * 64 + mt * 16 + l16];
#pragma unroll
      for (int nt = 0; nt < 4; ++nt)
        bf[nt] = Bs[ks * 512 + quad * 128 + wn * 64 + nt * 16 + l16];
#pragma unroll
      for (int mt = 0; mt < 4; ++mt)
#pragma unroll
        for (int nt = 0; nt < 4; ++nt)
          acc[mt][nt] = __builtin_amdgcn_mfma_f32_16x16x32_bf16(
              af[mt], bf[nt], acc[mt][nt], 0, 0, 0);
    }
  }

  const int col_base = N0 * 128 + wn * 64;
  const int row_base = M0 * 128 + wm * 64;
#pragma unroll
  for (int nt = 0; nt < 4; ++nt) {
    const int col = col_base + nt * 16 + l16;
    const float bv = bias[col];
#pragma unroll
    for (int mt = 0; mt < 4; ++mt) {
      floatx4 v = acc[mt][nt];
#pragma unroll
      for (int r4 = 0; r4 < 4; ++r4) {
        const int row = row_base + mt * 16 + quad * 4 + r4;
        out[(size_t)row * N_DIM + col] = v[r4] + bv;
      }
    }
  }
}

extern "C" void kernel_launch(void* const* d_in, const int* in_sizes, int n_in,
                              void* d_out, int out_size, void* d_ws, size_t ws_size,
                              hipStream_t stream) {
  const float* x = (const float*)d_in[0];     // 8192*4096
  const float* a = (const float*)d_in[1];     // 64*64*64 (r,i,j)
  const float* b = (const float*)d_in[2];     // 64*64*64 (r,k,l)
  const float* bias = (const float*)d_in[3];  // 4096
  float* out = (float*)d_out;

  unsigned short* Xp = (unsigned short*)d_ws;        // 67MB
  unsigned short* Wp = Xp + (size_t)M_DIM * K_DIM;   // 33.5MB

  prep_kernel<<<1024 + 8192, 256, 0, stream>>>(x, a, b, Xp, Wp);
  gemm_kernel<<<2048, 256, 0, stream>>>(Xp, Wp, bias, out);
}